// Round 1
// baseline (223.190 us; speedup 1.0000x reference)
//
#include <hip/hip_runtime.h>

#define IMG_W 512
#define IMG_H 512
#define RH    64            // output rows per block
#define KS    11
#define KR    5
#define OFF   8             // LDS left pad (>= KR)
#define LROW  (OFF + IMG_W + OFF)   // 528 floats per row buffer

// One block handles a full-width 512-col strip of RH output rows of one image.
// Pipeline over input rows: LDS-stage row -> horizontal 11-tap (5 fields) in
// registers -> 11-row register ring -> vertical 11-tap + SSIM in registers.
__global__ __launch_bounds__(256, 2)
void ssim_main(const float* __restrict__ xhat,
               const float* __restrict__ x,
               const float* __restrict__ kern,
               float* __restrict__ accum)
{
    __shared__ float rowA[LROW];
    __shared__ float rowB[LROW];
    __shared__ float red[4];

    const int tid   = threadIdx.x;
    const int c0    = tid << 1;           // this thread's 2 columns
    const int img   = blockIdx.x >> 3;    // 8 strips per image
    const int strip = blockIdx.x & 7;
    const int R0    = strip * RH;
    const float* xp = x    + (size_t)img * (IMG_W * IMG_H);
    const float* hp = xhat + (size_t)img * (IMG_W * IMG_H);

    // Separable 1D weights from the rank-1 2D kernel: g[i] = k[5][i]/sqrt(k[5][5])
    float g[KS];
    {
        const float inv = rsqrtf(kern[5 * KS + 5]);
        #pragma unroll
        for (int i = 0; i < KS; ++i) g[i] = kern[5 * KS + i] * inv;
    }

    // zero LDS pads once (never overwritten afterwards)
    if (tid < OFF) {
        rowA[tid] = 0.f;                rowB[tid] = 0.f;
        rowA[OFF + IMG_W + tid] = 0.f;  rowB[OFF + IMG_W + tid] = 0.f;
    }

    // ring buffer of horizontally-convolved rows: 5 fields x 11 rows x 2 cols
    float hist[5][KS][2];
    float acc = 0.f;
    const float C1 = 1e-4f, C2 = 9e-4f;

    // input rows rr in [0, 74); run to 77 (= 7*11) so the ring phase p is
    // compile-time constant (full unroll of the inner 11 phases)
    #pragma unroll 1
    for (int rblk = 0; rblk < 77; rblk += 11) {
        #pragma unroll
        for (int p = 0; p < KS; ++p) {
            const int rr = rblk + p;
            const bool active = (rr < RH + 2 * KR);   // block-uniform

            __syncthreads();   // previous iteration's readers done
            if (active) {
                const int ri = R0 - KR + rr;
                float a0 = 0.f, a1 = 0.f, b0 = 0.f, b1 = 0.f;
                if (ri >= 0 && ri < IMG_H) {
                    const float2 vx = *(const float2*)(xp + (size_t)ri * IMG_W + c0);
                    const float2 vh = *(const float2*)(hp + (size_t)ri * IMG_W + c0);
                    a0 = fmaf(vx.x, 0.5f, 0.5f);
                    a1 = fmaf(vx.y, 0.5f, 0.5f);
                    b0 = fmaf(vh.x, 0.5f, 0.5f);
                    b1 = fmaf(vh.y, 0.5f, 0.5f);
                }
                *(float2*)&rowA[OFF + c0] = make_float2(a0, a1);
                *(float2*)&rowB[OFF + c0] = make_float2(b0, b1);
            }
            __syncthreads();   // row staged

            if (active) {
                // ---- horizontal pass: 5 fields, 2 columns ----
                float h[5][2];
                #pragma unroll
                for (int f = 0; f < 5; ++f) { h[f][0] = 0.f; h[f][1] = 0.f; }
                const int ibase = OFF + c0 - KR;
                #pragma unroll
                for (int i = 0; i < KS + 1; ++i) {
                    const float pa  = rowA[ibase + i];
                    const float pb  = rowB[ibase + i];
                    const float paa = pa * pa;
                    const float pbb = pb * pb;
                    const float pab = pa * pb;
                    if (i < KS) {                 // contributes to col 0
                        const float w = g[i];
                        h[0][0] = fmaf(w, pa,  h[0][0]);
                        h[1][0] = fmaf(w, pb,  h[1][0]);
                        h[2][0] = fmaf(w, paa, h[2][0]);
                        h[3][0] = fmaf(w, pbb, h[3][0]);
                        h[4][0] = fmaf(w, pab, h[4][0]);
                    }
                    if (i > 0) {                  // contributes to col 1
                        const float w = g[i - 1];
                        h[0][1] = fmaf(w, pa,  h[0][1]);
                        h[1][1] = fmaf(w, pb,  h[1][1]);
                        h[2][1] = fmaf(w, paa, h[2][1]);
                        h[3][1] = fmaf(w, pbb, h[3][1]);
                        h[4][1] = fmaf(w, pab, h[4][1]);
                    }
                }
                #pragma unroll
                for (int f = 0; f < 5; ++f) {
                    hist[f][p][0] = h[f][0];
                    hist[f][p][1] = h[f][1];
                }

                // ---- vertical pass + SSIM once ring is full ----
                if (rr >= 2 * KR) {
                    float v[5][2];
                    #pragma unroll
                    for (int f = 0; f < 5; ++f) { v[f][0] = 0.f; v[f][1] = 0.f; }
                    #pragma unroll
                    for (int t = 0; t < KS; ++t) {
                        const int slot = (p + 1 + t) % KS;   // compile-time
                        const float w = g[t];
                        #pragma unroll
                        for (int f = 0; f < 5; ++f) {
                            v[f][0] = fmaf(w, hist[f][slot][0], v[f][0]);
                            v[f][1] = fmaf(w, hist[f][slot][1], v[f][1]);
                        }
                    }
                    #pragma unroll
                    for (int col = 0; col < 2; ++col) {
                        const float mux  = v[0][col], muy = v[1][col];
                        const float mux2 = mux * mux;
                        const float muy2 = muy * muy;
                        const float muxy = mux * muy;
                        const float sx   = v[2][col] - mux2;
                        const float sy   = v[3][col] - muy2;
                        const float sxy  = v[4][col] - muxy;
                        const float num  = (2.f * muxy + C1) * (2.f * sxy + C2);
                        const float den  = (mux2 + muy2 + C1) * (sx + sy + C2);
                        acc += num / (den + 1e-8f);
                    }
                }
            }
        }
    }

    // ---- block reduction: wave shuffle, then LDS across the 4 waves ----
    #pragma unroll
    for (int o = 32; o > 0; o >>= 1) acc += __shfl_down(acc, o, 64);
    if ((tid & 63) == 0) red[tid >> 6] = acc;
    __syncthreads();
    if (tid == 0) atomicAdd(accum, red[0] + red[1] + red[2] + red[3]);
}

__global__ void ssim_final(const float* __restrict__ accum,
                           float* __restrict__ out)
{
    out[0] = 1.0f - accum[0] * (1.0f / (64.0f * 512.0f * 512.0f));
}

extern "C" void kernel_launch(void* const* d_in, const int* in_sizes, int n_in,
                              void* d_out, int out_size, void* d_ws, size_t ws_size,
                              hipStream_t stream) {
    const float* xhat = (const float*)d_in[0];
    const float* xin  = (const float*)d_in[1];
    const float* kern = (const float*)d_in[2];
    float* out = (float*)d_out;
    float* ws  = (float*)d_ws;

    const int nimg   = in_sizes[0] / (IMG_W * IMG_H);   // 64
    const int strips = IMG_H / RH;                      // 8
    const int nblk   = nimg * strips;                   // 512

    hipMemsetAsync(ws, 0, sizeof(float), stream);
    ssim_main<<<nblk, 256, 0, stream>>>(xhat, xin, kern, ws);
    ssim_final<<<1, 1, 0, stream>>>(ws, out);
}